// Round 13
// baseline (154.362 us; speedup 1.0000x reference)
//
#include <hip/hip_runtime.h>
#include <hip/hip_bf16.h>
#include <math.h>

// Problem constants
#define D_BINS 59
#define CTX    80
#define O_TOT  139
#define K_CIN  256
#define PIXELS 704
#define BNPAIR 24
#define BEVHW  16384
#define NBATCH 4

// BEV binning: tile = 8 rows x 16 cols -> 128 cells, 128 tiles/batch.
#define NTILE   128
#define NBUCKET (NBATCH * NTILE)   // 512
#define TCELLS  128

// producer blocks: 16 px per 4-wave block; 24 bn * 44 ptiles.
#define PXT    16
#define NPXT   44                  // 704/16
#define NBLK   (BNPAIR * NPXT)     // 1056 regions
#define SEGS   (6 * NPXT)          // 264 segments per bucket
#define EPB    (PXT * D_BINS)      // 944 entries per region

#define CAP    2816
#define CAPP   (CAP + TCELLS * 7)  // 3712; pad-to-8 worst slack

// Workspace layout (4B units)
#define WHLF_OFF   0
#define WHLF_F     36864                           // W frags hi/lo, 147 KB
#define CTX_OFF    (WHLF_OFF + WHLF_F)
#define CTX_F      (BNPAIR * PIXELS * CTX / 2)     // 675,840
#define CNTMAT_OFF (CTX_OFF + CTX_F)               // transposed [NTILE][NBLK]
#define OFSMAT_OFF (CNTMAT_OFF + NTILE * NBLK)
#define PLIST_OFF  (OFSMAT_OFF + NTILE * NBLK)     // even -> uint2 aligned

typedef __attribute__((ext_vector_type(8))) short bf16x8;
typedef __attribute__((ext_vector_type(4))) float f32x4;

__device__ __forceinline__ unsigned short f2bf(float v) {
    __hip_bfloat16 h = __float2bfloat16(v);   // RNE
    return *reinterpret_cast<unsigned short*>(&h);
}
__device__ __forceinline__ float bf2f(unsigned short u) {
    return __uint_as_float(((unsigned)u) << 16);
}

// ---------------------------------------------------------------------------
// Kernel 0 (wsplit): W -> fragment-major bf16 hi/lo (r7/r8 layout, verified).
// ---------------------------------------------------------------------------
__global__ __launch_bounds__(256) void wsplit_kernel(
    const float* __restrict__ w, unsigned short* __restrict__ wf)
{
    const int row = blockIdx.x;        // 0..143
    const int col = threadIdx.x;       // 0..255
    const float v = (row < O_TOT) ? w[(size_t)row * K_CIN + col] : 0.f;
    const unsigned short hi = f2bf(v);
    const unsigned short lo = f2bf(v - bf2f(hi));
    const int t = row >> 4, m = row & 15;
    const int ks = col >> 5, kk = col & 31;
    const int g = kk >> 3, e = kk & 7;
    const size_t base = (size_t)(t * 8 + ks) * 1024 + (g * 16 + m) * 8 + e;
    wf[base]       = hi;
    wf[base + 512] = lo;
}

// ---------------------------------------------------------------------------
// K-loop: B fragments from LDS (conflict-free ds_read_b128), A fragments from
// the L2-hot fragment-major W slab. r8/r9-verified numerics.
// ---------------------------------------------------------------------------
template<int NT, int T0>
__device__ __forceinline__ void kloopL(
    const unsigned short* __restrict__ bst,   // LDS [ks][pl][512]
    const unsigned short* __restrict__ wf,
    int lane, f32x4* acc)
{
#pragma unroll 2
    for (int ks = 0; ks < 8; ++ks) {
        const bf16x8 bhi = *(const bf16x8*)&bst[ks * 1024 + lane * 8];
        const bf16x8 blo = *(const bf16x8*)&bst[ks * 1024 + 512 + lane * 8];
#pragma unroll
        for (int t = 0; t < NT; ++t) {
            const size_t ab = (size_t)((T0 + t) * 8 + ks) * 1024 + lane * 8;
            const bf16x8 ahi = *(const bf16x8*)&wf[ab];
            const bf16x8 alo = *(const bf16x8*)&wf[ab + 512];
            acc[t] = __builtin_amdgcn_mfma_f32_16x16x32_bf16(ahi, bhi, acc[t], 0, 0, 0);
            acc[t] = __builtin_amdgcn_mfma_f32_16x16x32_bf16(ahi, blo, acc[t], 0, 0, 0);
            acc[t] = __builtin_amdgcn_mfma_f32_16x16x32_bf16(alo, bhi, acc[t], 0, 0, 0);
        }
    }
}

// ---------------------------------------------------------------------------
// Kernel 1: EXACT r9/r11 version (4-wave tile-split blocks). Launched 2x this
// round (idempotent up to within-segment plist permutation) — ablation:
// Ggemm = T_r13 - T_r11.
// ---------------------------------------------------------------------------
__global__ __launch_bounds__(256, 4) void gemm_fused(
    const float* __restrict__ img,            // (24, 256, 704)
    const unsigned short* __restrict__ wf,    // W frags
    const float* __restrict__ bias,           // (139)
    const int*   __restrict__ geom,           // (24, 59, 704, 2)
    __hip_bfloat16* __restrict__ ctx,         // (24, 704, 80) bf16
    uint2*       __restrict__ plist,          // [NBLK][EPB]
    int*         __restrict__ cntmat_t,       // [NTILE][NBLK]
    int*         __restrict__ ofsmat_t)       // [NTILE][NBLK]
{
    __shared__ unsigned short bst[8192];      // 16 KB [ks][pl][512]
    __shared__ float hacc[2][64][8];          // 4 KB depth-tile handoff
    __shared__ int lh[NTILE], lofs[NTILE], lcur[NTILE];
    __shared__ unsigned short sctx[PXT][CTX]; // 2.5 KB

    const int tid  = threadIdx.x;
    const int lane = tid & 63;
    const int wv   = tid >> 6;                 // 0,1: depth; 2,3: ctx
    const int m    = lane & 15;
    const int g    = lane >> 4;                // == q for C-rows
    const int pt   = blockIdx.x;               // 0..43
    const int bn   = blockIdx.y;               // 0..23
    const int p0   = pt * PXT;
    const int pxg  = p0 + m;
    const int blkid = bn * NPXT + pt;

    // ---- stage img tile -> LDS fragments (b64-packed writes) ----
    {
        const float* ib = img + (size_t)bn * K_CIN * PIXELS + p0;
        const int px  = tid & 15;
        const int kq  = tid >> 4;              // 0..15
        const int e0  = (kq & 1) * 4;
        const int gg  = (kq >> 1) & 3;
        const int ksh = kq >> 3;               // 0..1
#pragma unroll
        for (int pass = 0; pass < 4; ++pass) {
            const int ks   = pass * 2 + ksh;
            const int krow = ks * 32 + gg * 8 + e0;
            float v[4];
#pragma unroll
            for (int j = 0; j < 4; ++j)
                v[j] = ib[(size_t)(krow + j) * PIXELS + px];
            uint2 hw, lw;
            {
                unsigned short h0 = f2bf(v[0]), h1 = f2bf(v[1]);
                unsigned short h2 = f2bf(v[2]), h3 = f2bf(v[3]);
                hw = make_uint2((unsigned)h0 | ((unsigned)h1 << 16),
                                (unsigned)h2 | ((unsigned)h3 << 16));
                unsigned short l0 = f2bf(v[0] - bf2f(h0)), l1 = f2bf(v[1] - bf2f(h1));
                unsigned short l2 = f2bf(v[2] - bf2f(h2)), l3 = f2bf(v[3] - bf2f(h3));
                lw = make_uint2((unsigned)l0 | ((unsigned)l1 << 16),
                                (unsigned)l2 | ((unsigned)l3 << 16));
            }
            const int base = ks * 1024 + (gg * 16 + px) * 8 + e0;
            *(uint2*)&bst[base]       = hw;
            *(uint2*)&bst[base + 512] = lw;
        }
    }
    if (tid < NTILE) { lh[tid] = 0; lcur[tid] = 0; }
    __syncthreads();   // SYNC1: B-tile staged

    f32x4 acc[3];
#pragma unroll
    for (int t = 0; t < 3; ++t) acc[t] = (f32x4){0.f, 0.f, 0.f, 0.f};

    if (wv == 0)      kloopL<2, 0>(bst, wf, lane, acc);
    else if (wv == 1) kloopL<2, 2>(bst, wf, lane, acc);
    else if (wv == 2) kloopL<3, 3>(bst, wf, lane, acc);
    else              kloopL<3, 6>(bst, wf, lane, acc);

    if (wv < 2) {
        // ========== depth waves ==========
        const bool own = (wv == 0) ? (m < 8) : (m >= 8);
        const int2* g2 = (const int2*)geom;
        int2 gg_[4][4];
#pragma unroll
        for (int t = 0; t < 4; ++t)
#pragma unroll
            for (int r = 0; r < 4; ++r) {
                const int o = 16 * t + 4 * g + r;
                if (o < D_BINS && own)
                    gg_[t][r] = g2[((size_t)(bn * D_BINS + o)) * PIXELS + pxg];
            }
#pragma unroll
        for (int t = 0; t < 2; ++t)
#pragma unroll
            for (int r = 0; r < 4; ++r) hacc[wv][lane][t * 4 + r] = acc[t][r];
        __syncthreads();   // SYNC2

        f32x4 facc[4];
        if (wv == 0) {
            facc[0] = acc[0]; facc[1] = acc[1];
#pragma unroll
            for (int r = 0; r < 4; ++r) {
                facc[2][r] = hacc[1][lane][r];
                facc[3][r] = hacc[1][lane][4 + r];
            }
        } else {
#pragma unroll
            for (int r = 0; r < 4; ++r) {
                facc[0][r] = hacc[0][lane][r];
                facc[1][r] = hacc[0][lane][4 + r];
            }
            facc[2] = acc[0]; facc[3] = acc[1];
        }

#pragma unroll
        for (int t = 0; t < 4; ++t)
#pragma unroll
            for (int r = 0; r < 4; ++r) facc[t][r] += bias[16 * t + 4 * g + r];

        float gm = -INFINITY;
#pragma unroll
        for (int t = 0; t < 4; ++t)
#pragma unroll
            for (int r = 0; r < 4; ++r)
                if (16 * t + 4 * g + r < D_BINS) gm = fmaxf(gm, facc[t][r]);
        gm = fmaxf(gm, __shfl_xor(gm, 16));
        gm = fmaxf(gm, __shfl_xor(gm, 32));
        float ls = 0.f;
#pragma unroll
        for (int t = 0; t < 4; ++t)
#pragma unroll
            for (int r = 0; r < 4; ++r)
                if (16 * t + 4 * g + r < D_BINS) {
                    const float e = __expf(facc[t][r] - gm);
                    facc[t][r] = e;
                    ls += e;
                }
        ls += __shfl_xor(ls, 16);
        ls += __shfl_xor(ls, 32);
        const float inv = 1.f / ls;

        unsigned uc[4][4];
#pragma unroll
        for (int t = 0; t < 4; ++t)
#pragma unroll
            for (int r = 0; r < 4; ++r) {
                const int o = 16 * t + 4 * g + r;
                if (o < D_BINS && own) {
                    const int2 q = gg_[t][r];
                    const int tile = (q.x >> 3) * 8 + (q.y >> 4);
                    const int cell = (q.x & 7) * 16 + (q.y & 15);
                    uc[t][r] = (unsigned)((tile << 7) | cell);
                    atomicAdd(&lh[tile], 1);
                }
            }
        __syncthreads();   // SYNC3

        if (wv == 0) {
            const int l2 = 2 * lane;
            const int a = lh[l2];
            const int b = lh[l2 + 1];
            const int p = a + b;
            int incl = p;
#pragma unroll
            for (int off = 1; off < 64; off <<= 1) {
                const int t = __shfl_up(incl, off);
                if (lane >= off) incl += t;
            }
            const int excl = incl - p;
            lofs[l2]     = excl;
            lofs[l2 + 1] = excl + a;
            cntmat_t[(size_t)l2 * NBLK + blkid]       = a;
            cntmat_t[(size_t)(l2 + 1) * NBLK + blkid] = b;
            ofsmat_t[(size_t)l2 * NBLK + blkid]       = excl;
            ofsmat_t[(size_t)(l2 + 1) * NBLK + blkid] = excl + a;
        }
        __syncthreads();   // SYNC4

        uint2* dst = plist + (size_t)blkid * EPB;
        const unsigned ctxoff = (unsigned)((bn * PIXELS + pxg) * CTX);
#pragma unroll
        for (int t = 0; t < 4; ++t)
#pragma unroll
            for (int r = 0; r < 4; ++r) {
                const int o = 16 * t + 4 * g + r;
                if (o < D_BINS && own) {
                    const unsigned u = uc[t][r];
                    const int tl = (int)(u >> 7);
                    const int pos = lofs[tl] + atomicAdd(&lcur[tl], 1);
                    dst[pos] = make_uint2(__float_as_uint(facc[t][r] * inv),
                                          (ctxoff << 7) | (u & 127u));
                }
            }
    } else {
        // ========== ctx waves ==========
        const int T0 = (wv == 2) ? 3 : 6;
#pragma unroll
        for (int t = 0; t < 3; ++t)
#pragma unroll
            for (int r = 0; r < 4; ++r) {
                const int o = (T0 + t) * 16 + 4 * g + r;     // 48..143
                const int c = o - D_BINS;                    // -11..84
                if (c >= 0 && c < CTX)
                    sctx[m][c] = f2bf(acc[t][r] + bias[o]);
            }
        __syncthreads();   // SYNC2

        const char* sb = (const char*)sctx;
        char* gb = (char*)ctx + ((size_t)(bn * PIXELS) + p0) * CTX * 2;
        for (int i = lane + (wv == 2 ? 0 : 64); i < PXT * CTX * 2 / 16; i += 128)
            *(float4*)(gb + i * 16) = *(const float4*)(sb + i * 16);

        __syncthreads();   // SYNC3
        __syncthreads();   // SYNC4
    }
}

// ---------------------------------------------------------------------------
// Kernel 2 (gather): EXACT r11 version (8-pt MLP accumulate, 1024 threads).
// ---------------------------------------------------------------------------
__global__ __launch_bounds__(1024) void gather_kernel(
    const uint2* __restrict__ plist,
    const int*   __restrict__ cntmat_t,   // [NTILE][NBLK]
    const int*   __restrict__ ofsmat_t,   // [NTILE][NBLK]
    const unsigned short* __restrict__ ctx,
    float*       __restrict__ out)
{
    __shared__ float sacc[CTX][TCELLS + 1];   // 41.3 KB
    __shared__ uint2 bufB[CAPP];              // 29.7 KB
    __shared__ int segcnt[SEGS], segofsL[SEGS], segofsG[SEGS];
    __shared__ int cellcnt[TCELLS], celloff[TCELLS], cellcur[TCELLS];
    __shared__ int sTotal;
    uint2* bufA = (uint2*)sacc;               // overlay: bufA dead once sacc live

    const int tid    = threadIdx.x;
    const int wv     = tid >> 6;
    const int lane   = tid & 63;
    const int bucket = blockIdx.x;
    const int b      = bucket >> 7;
    const int tile   = bucket & 127;
    const int blk0   = b * SEGS;

    // phase 1: coalesced metadata loads + cellcnt zero
    if (tid < SEGS) {
        segcnt[tid]  = cntmat_t[(size_t)tile * NBLK + blk0 + tid];
        segofsG[tid] = ofsmat_t[(size_t)tile * NBLK + blk0 + tid];
    }
    if (tid >= 512 && tid < 512 + TCELLS) cellcnt[tid - 512] = 0;
    __syncthreads();

    // phase 2: wave 0 shfl-scans the 264 segment counts (5 chunks, carry)
    if (wv == 0) {
        int carry = 0;
#pragma unroll
        for (int c = 0; c < 5; ++c) {
            const int i = c * 64 + lane;
            const int v = (i < SEGS) ? segcnt[i] : 0;
            int incl = v;
#pragma unroll
            for (int off = 1; off < 64; off <<= 1) {
                const int t = __shfl_up(incl, off);
                if (lane >= off) incl += t;
            }
            if (i < SEGS) segofsL[i] = carry + incl - v;
            carry += __shfl(incl, 63);
        }
        if (lane == 0) sTotal = carry;
    }
    __syncthreads();
    const int total = sTotal;
    const int ncap  = (total < CAP) ? total : CAP;

    // phase 3: copy segments -> bufA AND build LDS cell histogram (fused)
    {
        const int sub = lane >> 3;
        const int sl  = lane & 7;
        for (int sgi = wv * 8 + sub; sgi < SEGS; sgi += 128) {
            const int n = segcnt[sgi];
            if (!n) continue;
            const int dstb = segofsL[sgi];
            const uint2* sp = plist + (size_t)(blk0 + sgi) * EPB + segofsG[sgi];
            for (int i = sl; i < n; i += 8) {
                const int d = dstb + i;
                if (d < CAP) {
                    const uint2 e = sp[i];
                    bufA[d] = e;
                    atomicAdd(&cellcnt[e.y & 127u], 1);
                }
            }
        }
    }
    __syncthreads();

    // phase 4: wave 1 shfl-scans the 128 cell counts padded to 8
    if (wv == 1) {
        int carry = 0;
#pragma unroll
        for (int c = 0; c < 2; ++c) {
            const int i = c * 64 + lane;
            const int pv = (cellcnt[i] + 7) & ~7;
            int incl = pv;
#pragma unroll
            for (int off = 1; off < 64; off <<= 1) {
                const int t = __shfl_up(incl, off);
                if (lane >= off) incl += t;
            }
            celloff[i] = carry + incl - pv;
            cellcur[i] = 0;
            carry += __shfl(incl, 63);
        }
    }
    __syncthreads();

    // phase 5: zero pad slots (disjoint) + reorder bufA -> bufB cell-sorted
    if (tid < TCELLS) {
        const int o = celloff[tid] + cellcnt[tid];
        const int e = celloff[tid] + ((cellcnt[tid] + 7) & ~7);
        for (int i = o; i < e; ++i) bufB[i] = make_uint2(0u, 0u);
    }
    for (int i = tid; i < ncap; i += 1024) {
        const uint2 e = bufA[i];
        const int c = (int)(e.y & 127u);
        bufB[celloff[c] + atomicAdd(&cellcur[c], 1)] = e;
    }
    __syncthreads();   // bufA dead; sacc live from here

    // accumulate: wave wv owns cells c = wv, wv+16, ...; lane l<40 owns
    // channels (2l, 2l+1); 8-pt unrolled, 8 independent loads in flight.
    for (int c = wv; c < TCELLS; c += 16) {
        const int s0 = celloff[c];
        const int pc = (cellcnt[c] + 7) & ~7;
        float a0 = 0.f, a1 = 0.f;
        for (int i = 0; i < pc; i += 8) {
            uint2 e[8];
#pragma unroll
            for (int r = 0; r < 8; ++r) e[r] = bufB[s0 + i + r];   // broadcast
            if (lane < 40) {
                unsigned u[8];
#pragma unroll
                for (int r = 0; r < 8; ++r)
                    u[r] = *(const unsigned*)(ctx + (e[r].y >> 7) + 2 * lane);
#pragma unroll
                for (int r = 0; r < 8; ++r) {
                    const float d  = __uint_as_float(e[r].x);
                    a0 += d * __uint_as_float(u[r] << 16);
                    a1 += d * __uint_as_float(u[r] & 0xffff0000u);
                }
            }
        }
        if (lane < 40) {
            sacc[2 * lane][c]     = a0;
            sacc[2 * lane + 1][c] = a1;
        }
    }

    // slow path for bucket overflow (~30 sigma; correctness only)
    if (total > CAP) {
        for (int sgi = 0; sgi < SEGS; ++sgi) {
            const int dstb = segofsL[sgi];
            const int n    = segcnt[sgi];
            if (dstb + n <= CAP) continue;
            const uint2* sp = plist + (size_t)(blk0 + sgi) * EPB + segofsG[sgi];
            const int i0 = (CAP > dstb) ? (CAP - dstb) : 0;
            for (int i = i0; i < n; ++i) {
                const uint2 e = sp[i];
                const int c = (int)(e.y & 127u);
                if ((c & 15) == wv && lane < 40) {
                    const unsigned u = *(const unsigned*)(ctx + (e.y >> 7) + 2 * lane);
                    const float dep = __uint_as_float(e.x);
                    sacc[2 * lane][c]     += dep * __uint_as_float(u << 16);
                    sacc[2 * lane + 1][c] += dep * __uint_as_float(u & 0xffff0000u);
                }
            }
        }
    }
    __syncthreads();

    // epilogue: full 64B line writes to (B,C,H,W)
    const int tr = tile >> 3;
    const int tc = tile & 7;
    const int c0  = tid >> 4;
    const int col = tid & 15;
#pragma unroll
    for (int cc = c0; cc < CTX; cc += 64) {
#pragma unroll
        for (int r = 0; r < 8; ++r) {
            out[((size_t)(b * CTX + cc)) * BEVHW + (tr * 8 + r) * 128 + tc * 16 + col]
                = sacc[cc][r * 16 + col];
        }
    }
}

extern "C" void kernel_launch(void* const* d_in, const int* in_sizes, int n_in,
                              void* d_out, int out_size, void* d_ws, size_t ws_size,
                              hipStream_t stream)
{
    const float* img  = (const float*)d_in[0];
    const float* w    = (const float*)d_in[4];
    const float* bias = (const float*)d_in[5];
    const int*   geom = (const int*)d_in[6];
    float*       out  = (float*)d_out;

    float* ws = (float*)d_ws;
    unsigned short* wf = (unsigned short*)(ws + WHLF_OFF);
    __hip_bfloat16* ctx = (__hip_bfloat16*)(ws + CTX_OFF);
    int*   cntmat_t = (int*)(ws + CNTMAT_OFF);
    int*   ofsmat_t = (int*)(ws + OFSMAT_OFF);
    uint2* plist    = (uint2*)(ws + PLIST_OFF);

    // 0. W -> fragment-major bf16 hi/lo (147 KB, L2-resident)
    wsplit_kernel<<<144, 256, 0, stream>>>(w, wf);

    // 1. ABLATION: gemm launched 2x (idempotent up to within-segment order).
    //    Ggemm = T_r13 - T_r11.
    {
        dim3 grid(NPXT, BNPAIR);   // 1056 blocks x 256 threads
        gemm_fused<<<grid, 256, 0, stream>>>(img, wf, bias, geom, ctx,
                                             plist, cntmat_t, ofsmat_t);
        gemm_fused<<<grid, 256, 0, stream>>>(img, wf, bias, geom, ctx,
                                             plist, cntmat_t, ofsmat_t);
    }

    // 2. gather: r11-exact, single launch
    gather_kernel<<<NBUCKET, 1024, 0, stream>>>(plist, cntmat_t, ofsmat_t,
                                                (const unsigned short*)ctx, out);
}

// Round 14
// 147.470 us; speedup vs baseline: 1.0467x; 1.0467x over previous
//
#include <hip/hip_runtime.h>
#include <hip/hip_bf16.h>
#include <math.h>

// Problem constants
#define D_BINS 59
#define CTX    80
#define O_TOT  139
#define K_CIN  256
#define PIXELS 704
#define BNPAIR 24
#define BEVHW  16384
#define NBATCH 4

// BEV binning: tile = 8 rows x 16 cols -> 128 cells, 128 tiles/batch.
#define NTILE   128
#define NBUCKET (NBATCH * NTILE)   // 512
#define TCELLS  128

// producer blocks: 16 px per 4-wave block; 24 bn * 44 ptiles.
#define PXT    16
#define NPXT   44                  // 704/16
#define NBLK   (BNPAIR * NPXT)     // 1056 regions
#define SEGS   (6 * NPXT)          // 264 segments per bucket
#define EPB    (PXT * D_BINS)      // 944 entries per region

#define CAP    2816
#define CAPP   (CAP + TCELLS * 7)  // 3712; pad-to-8 worst slack

// Workspace layout (4B units)
#define CTX_OFF    0
#define CTX_F      (BNPAIR * PIXELS * CTX / 2)     // 675,840
#define CNTMAT_OFF (CTX_OFF + CTX_F)               // transposed [NTILE][NBLK]
#define OFSMAT_OFF (CNTMAT_OFF + NTILE * NBLK)
#define PLIST_OFF  (OFSMAT_OFF + NTILE * NBLK)     // even -> uint2 aligned

typedef __attribute__((ext_vector_type(8))) short bf16x8;
typedef __attribute__((ext_vector_type(4))) float f32x4;

__device__ __forceinline__ unsigned short f2bf(float v) {
    __hip_bfloat16 h = __float2bfloat16(v);   // RNE
    return *reinterpret_cast<unsigned short*>(&h);
}
__device__ __forceinline__ float bf2f(unsigned short u) {
    return __uint_as_float(((unsigned)u) << 16);
}

// ---------------------------------------------------------------------------
// K-loop: B fragments from LDS (conflict-free ds_read_b128); A fragments
// loaded as fp32 W rows and hi/lo-split IN-REGISTER (identical f2bf ops to
// the former wsplit kernel -> bitwise-same operands; rows >= O_TOT zeroed,
// matching wsplit's padding). MFMA order unchanged (verified numerics).
// W is 142 KB -> L2-resident; per-block traffic matches the old wf slab.
// ---------------------------------------------------------------------------
template<int NT, int T0>
__device__ __forceinline__ void kloopW(
    const unsigned short* __restrict__ bst,   // LDS [ks][pl][512]
    const float* __restrict__ w,              // (139, 256) fp32
    int lane, f32x4* acc)
{
    const int m = lane & 15;
    const int g = lane >> 4;
#pragma unroll 2
    for (int ks = 0; ks < 8; ++ks) {
        const bf16x8 bhi = *(const bf16x8*)&bst[ks * 1024 + lane * 8];
        const bf16x8 blo = *(const bf16x8*)&bst[ks * 1024 + 512 + lane * 8];
#pragma unroll
        for (int t = 0; t < NT; ++t) {
            const int row = (T0 + t) * 16 + m;
            float v[8];
            if (row < O_TOT) {
                const float4 a = *(const float4*)&w[(size_t)row * K_CIN + ks * 32 + g * 8];
                const float4 b = *(const float4*)&w[(size_t)row * K_CIN + ks * 32 + g * 8 + 4];
                v[0] = a.x; v[1] = a.y; v[2] = a.z; v[3] = a.w;
                v[4] = b.x; v[5] = b.y; v[6] = b.z; v[7] = b.w;
            } else {
#pragma unroll
                for (int j = 0; j < 8; ++j) v[j] = 0.f;
            }
            bf16x8 ahi, alo;
#pragma unroll
            for (int j = 0; j < 8; ++j) {
                const unsigned short h = f2bf(v[j]);
                ahi[j] = (short)h;
                alo[j] = (short)f2bf(v[j] - bf2f(h));
            }
            acc[t] = __builtin_amdgcn_mfma_f32_16x16x32_bf16(ahi, bhi, acc[t], 0, 0, 0);
            acc[t] = __builtin_amdgcn_mfma_f32_16x16x32_bf16(ahi, blo, acc[t], 0, 0, 0);
            acc[t] = __builtin_amdgcn_mfma_f32_16x16x32_bf16(alo, bhi, acc[t], 0, 0, 0);
        }
    }
}

// ---------------------------------------------------------------------------
// Kernel 1: r9/r11 4-wave tile-split structure; W conversion folded in
// (wsplit dispatch removed). Everything else r11-byte-equivalent.
// ---------------------------------------------------------------------------
__global__ __launch_bounds__(256, 4) void gemm_fused(
    const float* __restrict__ img,            // (24, 256, 704)
    const float* __restrict__ w,              // (139, 256) fp32
    const float* __restrict__ bias,           // (139)
    const int*   __restrict__ geom,           // (24, 59, 704, 2)
    __hip_bfloat16* __restrict__ ctx,         // (24, 704, 80) bf16
    uint2*       __restrict__ plist,          // [NBLK][EPB]
    int*         __restrict__ cntmat_t,       // [NTILE][NBLK]
    int*         __restrict__ ofsmat_t)       // [NTILE][NBLK]
{
    __shared__ unsigned short bst[8192];      // 16 KB [ks][pl][512]
    __shared__ float hacc[2][64][8];          // 4 KB depth-tile handoff
    __shared__ int lh[NTILE], lofs[NTILE], lcur[NTILE];
    __shared__ unsigned short sctx[PXT][CTX]; // 2.5 KB

    const int tid  = threadIdx.x;
    const int lane = tid & 63;
    const int wv   = tid >> 6;                 // 0,1: depth; 2,3: ctx
    const int m    = lane & 15;
    const int g    = lane >> 4;                // == q for C-rows
    const int pt   = blockIdx.x;               // 0..43
    const int bn   = blockIdx.y;               // 0..23
    const int p0   = pt * PXT;
    const int pxg  = p0 + m;
    const int blkid = bn * NPXT + pt;

    // ---- stage img tile -> LDS fragments (b64-packed writes) ----
    {
        const float* ib = img + (size_t)bn * K_CIN * PIXELS + p0;
        const int px  = tid & 15;
        const int kq  = tid >> 4;              // 0..15
        const int e0  = (kq & 1) * 4;
        const int gg  = (kq >> 1) & 3;
        const int ksh = kq >> 3;               // 0..1
#pragma unroll
        for (int pass = 0; pass < 4; ++pass) {
            const int ks   = pass * 2 + ksh;
            const int krow = ks * 32 + gg * 8 + e0;
            float v[4];
#pragma unroll
            for (int j = 0; j < 4; ++j)
                v[j] = ib[(size_t)(krow + j) * PIXELS + px];
            uint2 hw, lw;
            {
                unsigned short h0 = f2bf(v[0]), h1 = f2bf(v[1]);
                unsigned short h2 = f2bf(v[2]), h3 = f2bf(v[3]);
                hw = make_uint2((unsigned)h0 | ((unsigned)h1 << 16),
                                (unsigned)h2 | ((unsigned)h3 << 16));
                unsigned short l0 = f2bf(v[0] - bf2f(h0)), l1 = f2bf(v[1] - bf2f(h1));
                unsigned short l2 = f2bf(v[2] - bf2f(h2)), l3 = f2bf(v[3] - bf2f(h3));
                lw = make_uint2((unsigned)l0 | ((unsigned)l1 << 16),
                                (unsigned)l2 | ((unsigned)l3 << 16));
            }
            const int base = ks * 1024 + (gg * 16 + px) * 8 + e0;
            *(uint2*)&bst[base]       = hw;
            *(uint2*)&bst[base + 512] = lw;
        }
    }
    if (tid < NTILE) { lh[tid] = 0; lcur[tid] = 0; }
    __syncthreads();   // SYNC1: B-tile staged

    f32x4 acc[3];
#pragma unroll
    for (int t = 0; t < 3; ++t) acc[t] = (f32x4){0.f, 0.f, 0.f, 0.f};

    if (wv == 0)      kloopW<2, 0>(bst, w, lane, acc);
    else if (wv == 1) kloopW<2, 2>(bst, w, lane, acc);
    else if (wv == 2) kloopW<3, 3>(bst, w, lane, acc);
    else              kloopW<3, 6>(bst, w, lane, acc);

    if (wv < 2) {
        // ========== depth waves ==========
        const bool own = (wv == 0) ? (m < 8) : (m >= 8);
        const int2* g2 = (const int2*)geom;
        int2 gg_[4][4];
#pragma unroll
        for (int t = 0; t < 4; ++t)
#pragma unroll
            for (int r = 0; r < 4; ++r) {
                const int o = 16 * t + 4 * g + r;
                if (o < D_BINS && own)
                    gg_[t][r] = g2[((size_t)(bn * D_BINS + o)) * PIXELS + pxg];
            }
#pragma unroll
        for (int t = 0; t < 2; ++t)
#pragma unroll
            for (int r = 0; r < 4; ++r) hacc[wv][lane][t * 4 + r] = acc[t][r];
        __syncthreads();   // SYNC2

        f32x4 facc[4];
        if (wv == 0) {
            facc[0] = acc[0]; facc[1] = acc[1];
#pragma unroll
            for (int r = 0; r < 4; ++r) {
                facc[2][r] = hacc[1][lane][r];
                facc[3][r] = hacc[1][lane][4 + r];
            }
        } else {
#pragma unroll
            for (int r = 0; r < 4; ++r) {
                facc[0][r] = hacc[0][lane][r];
                facc[1][r] = hacc[0][lane][4 + r];
            }
            facc[2] = acc[0]; facc[3] = acc[1];
        }

#pragma unroll
        for (int t = 0; t < 4; ++t)
#pragma unroll
            for (int r = 0; r < 4; ++r) facc[t][r] += bias[16 * t + 4 * g + r];

        float gm = -INFINITY;
#pragma unroll
        for (int t = 0; t < 4; ++t)
#pragma unroll
            for (int r = 0; r < 4; ++r)
                if (16 * t + 4 * g + r < D_BINS) gm = fmaxf(gm, facc[t][r]);
        gm = fmaxf(gm, __shfl_xor(gm, 16));
        gm = fmaxf(gm, __shfl_xor(gm, 32));
        float ls = 0.f;
#pragma unroll
        for (int t = 0; t < 4; ++t)
#pragma unroll
            for (int r = 0; r < 4; ++r)
                if (16 * t + 4 * g + r < D_BINS) {
                    const float e = __expf(facc[t][r] - gm);
                    facc[t][r] = e;
                    ls += e;
                }
        ls += __shfl_xor(ls, 16);
        ls += __shfl_xor(ls, 32);
        const float inv = 1.f / ls;

        unsigned uc[4][4];
#pragma unroll
        for (int t = 0; t < 4; ++t)
#pragma unroll
            for (int r = 0; r < 4; ++r) {
                const int o = 16 * t + 4 * g + r;
                if (o < D_BINS && own) {
                    const int2 q = gg_[t][r];
                    const int tile = (q.x >> 3) * 8 + (q.y >> 4);
                    const int cell = (q.x & 7) * 16 + (q.y & 15);
                    uc[t][r] = (unsigned)((tile << 7) | cell);
                    atomicAdd(&lh[tile], 1);
                }
            }
        __syncthreads();   // SYNC3

        if (wv == 0) {
            const int l2 = 2 * lane;
            const int a = lh[l2];
            const int b = lh[l2 + 1];
            const int p = a + b;
            int incl = p;
#pragma unroll
            for (int off = 1; off < 64; off <<= 1) {
                const int t = __shfl_up(incl, off);
                if (lane >= off) incl += t;
            }
            const int excl = incl - p;
            lofs[l2]     = excl;
            lofs[l2 + 1] = excl + a;
            cntmat_t[(size_t)l2 * NBLK + blkid]       = a;
            cntmat_t[(size_t)(l2 + 1) * NBLK + blkid] = b;
            ofsmat_t[(size_t)l2 * NBLK + blkid]       = excl;
            ofsmat_t[(size_t)(l2 + 1) * NBLK + blkid] = excl + a;
        }
        __syncthreads();   // SYNC4

        uint2* dst = plist + (size_t)blkid * EPB;
        const unsigned ctxoff = (unsigned)((bn * PIXELS + pxg) * CTX);
#pragma unroll
        for (int t = 0; t < 4; ++t)
#pragma unroll
            for (int r = 0; r < 4; ++r) {
                const int o = 16 * t + 4 * g + r;
                if (o < D_BINS && own) {
                    const unsigned u = uc[t][r];
                    const int tl = (int)(u >> 7);
                    const int pos = lofs[tl] + atomicAdd(&lcur[tl], 1);
                    dst[pos] = make_uint2(__float_as_uint(facc[t][r] * inv),
                                          (ctxoff << 7) | (u & 127u));
                }
            }
    } else {
        // ========== ctx waves ==========
        const int T0 = (wv == 2) ? 3 : 6;
#pragma unroll
        for (int t = 0; t < 3; ++t)
#pragma unroll
            for (int r = 0; r < 4; ++r) {
                const int o = (T0 + t) * 16 + 4 * g + r;     // 48..143
                const int c = o - D_BINS;                    // -11..84
                if (c >= 0 && c < CTX)
                    sctx[m][c] = f2bf(acc[t][r] + bias[o]);
            }
        __syncthreads();   // SYNC2

        const char* sb = (const char*)sctx;
        char* gb = (char*)ctx + ((size_t)(bn * PIXELS) + p0) * CTX * 2;
        for (int i = lane + (wv == 2 ? 0 : 64); i < PXT * CTX * 2 / 16; i += 128)
            *(float4*)(gb + i * 16) = *(const float4*)(sb + i * 16);

        __syncthreads();   // SYNC3
        __syncthreads();   // SYNC4
    }
}

// ---------------------------------------------------------------------------
// Kernel 2 (gather): EXACT r11 version (8-pt MLP accumulate, 1024 threads).
// ---------------------------------------------------------------------------
__global__ __launch_bounds__(1024) void gather_kernel(
    const uint2* __restrict__ plist,
    const int*   __restrict__ cntmat_t,   // [NTILE][NBLK]
    const int*   __restrict__ ofsmat_t,   // [NTILE][NBLK]
    const unsigned short* __restrict__ ctx,
    float*       __restrict__ out)
{
    __shared__ float sacc[CTX][TCELLS + 1];   // 41.3 KB
    __shared__ uint2 bufB[CAPP];              // 29.7 KB
    __shared__ int segcnt[SEGS], segofsL[SEGS], segofsG[SEGS];
    __shared__ int cellcnt[TCELLS], celloff[TCELLS], cellcur[TCELLS];
    __shared__ int sTotal;
    uint2* bufA = (uint2*)sacc;               // overlay: bufA dead once sacc live

    const int tid    = threadIdx.x;
    const int wv     = tid >> 6;
    const int lane   = tid & 63;
    const int bucket = blockIdx.x;
    const int b      = bucket >> 7;
    const int tile   = bucket & 127;
    const int blk0   = b * SEGS;

    // phase 1: coalesced metadata loads + cellcnt zero
    if (tid < SEGS) {
        segcnt[tid]  = cntmat_t[(size_t)tile * NBLK + blk0 + tid];
        segofsG[tid] = ofsmat_t[(size_t)tile * NBLK + blk0 + tid];
    }
    if (tid >= 512 && tid < 512 + TCELLS) cellcnt[tid - 512] = 0;
    __syncthreads();

    // phase 2: wave 0 shfl-scans the 264 segment counts (5 chunks, carry)
    if (wv == 0) {
        int carry = 0;
#pragma unroll
        for (int c = 0; c < 5; ++c) {
            const int i = c * 64 + lane;
            const int v = (i < SEGS) ? segcnt[i] : 0;
            int incl = v;
#pragma unroll
            for (int off = 1; off < 64; off <<= 1) {
                const int t = __shfl_up(incl, off);
                if (lane >= off) incl += t;
            }
            if (i < SEGS) segofsL[i] = carry + incl - v;
            carry += __shfl(incl, 63);
        }
        if (lane == 0) sTotal = carry;
    }
    __syncthreads();
    const int total = sTotal;
    const int ncap  = (total < CAP) ? total : CAP;

    // phase 3: copy segments -> bufA AND build LDS cell histogram (fused)
    {
        const int sub = lane >> 3;
        const int sl  = lane & 7;
        for (int sgi = wv * 8 + sub; sgi < SEGS; sgi += 128) {
            const int n = segcnt[sgi];
            if (!n) continue;
            const int dstb = segofsL[sgi];
            const uint2* sp = plist + (size_t)(blk0 + sgi) * EPB + segofsG[sgi];
            for (int i = sl; i < n; i += 8) {
                const int d = dstb + i;
                if (d < CAP) {
                    const uint2 e = sp[i];
                    bufA[d] = e;
                    atomicAdd(&cellcnt[e.y & 127u], 1);
                }
            }
        }
    }
    __syncthreads();

    // phase 4: wave 1 shfl-scans the 128 cell counts padded to 8
    if (wv == 1) {
        int carry = 0;
#pragma unroll
        for (int c = 0; c < 2; ++c) {
            const int i = c * 64 + lane;
            const int pv = (cellcnt[i] + 7) & ~7;
            int incl = pv;
#pragma unroll
            for (int off = 1; off < 64; off <<= 1) {
                const int t = __shfl_up(incl, off);
                if (lane >= off) incl += t;
            }
            celloff[i] = carry + incl - pv;
            cellcur[i] = 0;
            carry += __shfl(incl, 63);
        }
    }
    __syncthreads();

    // phase 5: zero pad slots (disjoint) + reorder bufA -> bufB cell-sorted
    if (tid < TCELLS) {
        const int o = celloff[tid] + cellcnt[tid];
        const int e = celloff[tid] + ((cellcnt[tid] + 7) & ~7);
        for (int i = o; i < e; ++i) bufB[i] = make_uint2(0u, 0u);
    }
    for (int i = tid; i < ncap; i += 1024) {
        const uint2 e = bufA[i];
        const int c = (int)(e.y & 127u);
        bufB[celloff[c] + atomicAdd(&cellcur[c], 1)] = e;
    }
    __syncthreads();   // bufA dead; sacc live from here

    // accumulate: wave wv owns cells c = wv, wv+16, ...; lane l<40 owns
    // channels (2l, 2l+1); 8-pt unrolled, 8 independent loads in flight.
    for (int c = wv; c < TCELLS; c += 16) {
        const int s0 = celloff[c];
        const int pc = (cellcnt[c] + 7) & ~7;
        float a0 = 0.f, a1 = 0.f;
        for (int i = 0; i < pc; i += 8) {
            uint2 e[8];
#pragma unroll
            for (int r = 0; r < 8; ++r) e[r] = bufB[s0 + i + r];   // broadcast
            if (lane < 40) {
                unsigned u[8];
#pragma unroll
                for (int r = 0; r < 8; ++r)
                    u[r] = *(const unsigned*)(ctx + (e[r].y >> 7) + 2 * lane);
#pragma unroll
                for (int r = 0; r < 8; ++r) {
                    const float d  = __uint_as_float(e[r].x);
                    a0 += d * __uint_as_float(u[r] << 16);
                    a1 += d * __uint_as_float(u[r] & 0xffff0000u);
                }
            }
        }
        if (lane < 40) {
            sacc[2 * lane][c]     = a0;
            sacc[2 * lane + 1][c] = a1;
        }
    }

    // slow path for bucket overflow (~30 sigma; correctness only)
    if (total > CAP) {
        for (int sgi = 0; sgi < SEGS; ++sgi) {
            const int dstb = segofsL[sgi];
            const int n    = segcnt[sgi];
            if (dstb + n <= CAP) continue;
            const uint2* sp = plist + (size_t)(blk0 + sgi) * EPB + segofsG[sgi];
            const int i0 = (CAP > dstb) ? (CAP - dstb) : 0;
            for (int i = i0; i < n; ++i) {
                const uint2 e = sp[i];
                const int c = (int)(e.y & 127u);
                if ((c & 15) == wv && lane < 40) {
                    const unsigned u = *(const unsigned*)(ctx + (e.y >> 7) + 2 * lane);
                    const float dep = __uint_as_float(e.x);
                    sacc[2 * lane][c]     += dep * __uint_as_float(u << 16);
                    sacc[2 * lane + 1][c] += dep * __uint_as_float(u & 0xffff0000u);
                }
            }
        }
    }
    __syncthreads();

    // epilogue: full 64B line writes to (B,C,H,W)
    const int tr = tile >> 3;
    const int tc = tile & 7;
    const int c0  = tid >> 4;
    const int col = tid & 15;
#pragma unroll
    for (int cc = c0; cc < CTX; cc += 64) {
#pragma unroll
        for (int r = 0; r < 8; ++r) {
            out[((size_t)(b * CTX + cc)) * BEVHW + (tr * 8 + r) * 128 + tc * 16 + col]
                = sacc[cc][r * 16 + col];
        }
    }
}

extern "C" void kernel_launch(void* const* d_in, const int* in_sizes, int n_in,
                              void* d_out, int out_size, void* d_ws, size_t ws_size,
                              hipStream_t stream)
{
    const float* img  = (const float*)d_in[0];
    const float* w    = (const float*)d_in[4];
    const float* bias = (const float*)d_in[5];
    const int*   geom = (const int*)d_in[6];
    float*       out  = (float*)d_out;

    float* ws = (float*)d_ws;
    __hip_bfloat16* ctx = (__hip_bfloat16*)(ws + CTX_OFF);
    int*   cntmat_t = (int*)(ws + CNTMAT_OFF);
    int*   ofsmat_t = (int*)(ws + OFSMAT_OFF);
    uint2* plist    = (uint2*)(ws + PLIST_OFF);

    // 1. 4-wave blocks; W converted in-register (wsplit dispatch removed)
    {
        dim3 grid(NPXT, BNPAIR);   // 1056 blocks x 256 threads
        gemm_fused<<<grid, 256, 0, stream>>>(img, w, bias, geom, ctx,
                                             plist, cntmat_t, ofsmat_t);
    }

    // 2. gather: r11-exact, single launch
    gather_kernel<<<NBUCKET, 1024, 0, stream>>>(plist, cntmat_t, ofsmat_t,
                                                (const unsigned short*)ctx, out);
}

// Round 15
// 131.572 us; speedup vs baseline: 1.1732x; 1.1208x over previous
//
#include <hip/hip_runtime.h>
#include <hip/hip_bf16.h>
#include <math.h>

// Problem constants
#define D_BINS 59
#define CTX    80
#define O_TOT  139
#define K_CIN  256
#define PIXELS 704
#define BNPAIR 24
#define BEVHW  16384
#define NBATCH 4

// BEV binning: tile = 8 rows x 16 cols -> 128 cells, 128 tiles/batch.
#define NTILE   128
#define NBUCKET (NBATCH * NTILE)   // 512
#define TCELLS  128

// producer blocks: 16 px per 4-wave block; 24 bn * 44 ptiles.
#define PXT    16
#define NPXT   44                  // 704/16
#define NBLK   (BNPAIR * NPXT)     // 1056 regions
#define SEGS   (6 * NPXT)          // 264 segments per bucket
#define EPB    (PXT * D_BINS)      // 944 entries per region

#define CAP    2816
#define CAPP   (CAP + TCELLS * 7)  // 3712; pad-to-8 worst slack

// Workspace layout (4B units)
#define WHLF_OFF   0
#define WHLF_F     36864                           // W frags hi/lo, 147 KB
#define CTX_OFF    (WHLF_OFF + WHLF_F)
#define CTX_F      (BNPAIR * PIXELS * CTX / 2)     // 675,840
#define CNTMAT_OFF (CTX_OFF + CTX_F)               // transposed [NTILE][NBLK]
#define OFSMAT_OFF (CNTMAT_OFF + NTILE * NBLK)
#define PLIST_OFF  (OFSMAT_OFF + NTILE * NBLK)     // even -> uint2 aligned

typedef __attribute__((ext_vector_type(8))) short bf16x8;
typedef __attribute__((ext_vector_type(4))) float f32x4;

__device__ __forceinline__ unsigned short f2bf(float v) {
    __hip_bfloat16 h = __float2bfloat16(v);   // RNE
    return *reinterpret_cast<unsigned short*>(&h);
}
__device__ __forceinline__ float bf2f(unsigned short u) {
    return __uint_as_float(((unsigned)u) << 16);
}

// ---------------------------------------------------------------------------
// Kernel 0 (wsplit): W -> fragment-major bf16 hi/lo (r7/r8 layout, verified).
// Re-proven essential by r14: in-register W conversion re-scatters A-fetch
// (45.2 us measured) vs 1.5 us for this kernel + L2-hot coalesced slab reads.
// ---------------------------------------------------------------------------
__global__ __launch_bounds__(256) void wsplit_kernel(
    const float* __restrict__ w, unsigned short* __restrict__ wf)
{
    const int row = blockIdx.x;        // 0..143
    const int col = threadIdx.x;       // 0..255
    const float v = (row < O_TOT) ? w[(size_t)row * K_CIN + col] : 0.f;
    const unsigned short hi = f2bf(v);
    const unsigned short lo = f2bf(v - bf2f(hi));
    const int t = row >> 4, m = row & 15;
    const int ks = col >> 5, kk = col & 31;
    const int g = kk >> 3, e = kk & 7;
    const size_t base = (size_t)(t * 8 + ks) * 1024 + (g * 16 + m) * 8 + e;
    wf[base]       = hi;
    wf[base + 512] = lo;
}

// ---------------------------------------------------------------------------
// K-loop: B fragments from LDS (conflict-free ds_read_b128), A fragments from
// the L2-hot fragment-major W slab. r8/r9/r11-verified numerics.
// ---------------------------------------------------------------------------
template<int NT, int T0>
__device__ __forceinline__ void kloopL(
    const unsigned short* __restrict__ bst,   // LDS [ks][pl][512]
    const unsigned short* __restrict__ wf,
    int lane, f32x4* acc)
{
#pragma unroll 2
    for (int ks = 0; ks < 8; ++ks) {
        const bf16x8 bhi = *(const bf16x8*)&bst[ks * 1024 + lane * 8];
        const bf16x8 blo = *(const bf16x8*)&bst[ks * 1024 + 512 + lane * 8];
#pragma unroll
        for (int t = 0; t < NT; ++t) {
            const size_t ab = (size_t)((T0 + t) * 8 + ks) * 1024 + lane * 8;
            const bf16x8 ahi = *(const bf16x8*)&wf[ab];
            const bf16x8 alo = *(const bf16x8*)&wf[ab + 512];
            acc[t] = __builtin_amdgcn_mfma_f32_16x16x32_bf16(ahi, bhi, acc[t], 0, 0, 0);
            acc[t] = __builtin_amdgcn_mfma_f32_16x16x32_bf16(ahi, blo, acc[t], 0, 0, 0);
            acc[t] = __builtin_amdgcn_mfma_f32_16x16x32_bf16(alo, bhi, acc[t], 0, 0, 0);
        }
    }
}

// ---------------------------------------------------------------------------
// Kernel 1: EXACT r11 version (4-wave tile-split blocks) — session best.
// ---------------------------------------------------------------------------
__global__ __launch_bounds__(256, 4) void gemm_fused(
    const float* __restrict__ img,            // (24, 256, 704)
    const unsigned short* __restrict__ wf,    // W frags
    const float* __restrict__ bias,           // (139)
    const int*   __restrict__ geom,           // (24, 59, 704, 2)
    __hip_bfloat16* __restrict__ ctx,         // (24, 704, 80) bf16
    uint2*       __restrict__ plist,          // [NBLK][EPB]
    int*         __restrict__ cntmat_t,       // [NTILE][NBLK]
    int*         __restrict__ ofsmat_t)       // [NTILE][NBLK]
{
    __shared__ unsigned short bst[8192];      // 16 KB [ks][pl][512]
    __shared__ float hacc[2][64][8];          // 4 KB depth-tile handoff
    __shared__ int lh[NTILE], lofs[NTILE], lcur[NTILE];
    __shared__ unsigned short sctx[PXT][CTX]; // 2.5 KB

    const int tid  = threadIdx.x;
    const int lane = tid & 63;
    const int wv   = tid >> 6;                 // 0,1: depth; 2,3: ctx
    const int m    = lane & 15;
    const int g    = lane >> 4;                // == q for C-rows
    const int pt   = blockIdx.x;               // 0..43
    const int bn   = blockIdx.y;               // 0..23
    const int p0   = pt * PXT;
    const int pxg  = p0 + m;
    const int blkid = bn * NPXT + pt;

    // ---- stage img tile -> LDS fragments (b64-packed writes) ----
    {
        const float* ib = img + (size_t)bn * K_CIN * PIXELS + p0;
        const int px  = tid & 15;
        const int kq  = tid >> 4;              // 0..15
        const int e0  = (kq & 1) * 4;
        const int gg  = (kq >> 1) & 3;
        const int ksh = kq >> 3;               // 0..1
#pragma unroll
        for (int pass = 0; pass < 4; ++pass) {
            const int ks   = pass * 2 + ksh;
            const int krow = ks * 32 + gg * 8 + e0;
            float v[4];
#pragma unroll
            for (int j = 0; j < 4; ++j)
                v[j] = ib[(size_t)(krow + j) * PIXELS + px];
            uint2 hw, lw;
            {
                unsigned short h0 = f2bf(v[0]), h1 = f2bf(v[1]);
                unsigned short h2 = f2bf(v[2]), h3 = f2bf(v[3]);
                hw = make_uint2((unsigned)h0 | ((unsigned)h1 << 16),
                                (unsigned)h2 | ((unsigned)h3 << 16));
                unsigned short l0 = f2bf(v[0] - bf2f(h0)), l1 = f2bf(v[1] - bf2f(h1));
                unsigned short l2 = f2bf(v[2] - bf2f(h2)), l3 = f2bf(v[3] - bf2f(h3));
                lw = make_uint2((unsigned)l0 | ((unsigned)l1 << 16),
                                (unsigned)l2 | ((unsigned)l3 << 16));
            }
            const int base = ks * 1024 + (gg * 16 + px) * 8 + e0;
            *(uint2*)&bst[base]       = hw;
            *(uint2*)&bst[base + 512] = lw;
        }
    }
    if (tid < NTILE) { lh[tid] = 0; lcur[tid] = 0; }
    __syncthreads();   // SYNC1: B-tile staged

    f32x4 acc[3];
#pragma unroll
    for (int t = 0; t < 3; ++t) acc[t] = (f32x4){0.f, 0.f, 0.f, 0.f};

    if (wv == 0)      kloopL<2, 0>(bst, wf, lane, acc);
    else if (wv == 1) kloopL<2, 2>(bst, wf, lane, acc);
    else if (wv == 2) kloopL<3, 3>(bst, wf, lane, acc);
    else              kloopL<3, 6>(bst, wf, lane, acc);

    if (wv < 2) {
        // ========== depth waves ==========
        const bool own = (wv == 0) ? (m < 8) : (m >= 8);
        const int2* g2 = (const int2*)geom;
        int2 gg_[4][4];
#pragma unroll
        for (int t = 0; t < 4; ++t)
#pragma unroll
            for (int r = 0; r < 4; ++r) {
                const int o = 16 * t + 4 * g + r;
                if (o < D_BINS && own)
                    gg_[t][r] = g2[((size_t)(bn * D_BINS + o)) * PIXELS + pxg];
            }
#pragma unroll
        for (int t = 0; t < 2; ++t)
#pragma unroll
            for (int r = 0; r < 4; ++r) hacc[wv][lane][t * 4 + r] = acc[t][r];
        __syncthreads();   // SYNC2

        f32x4 facc[4];
        if (wv == 0) {
            facc[0] = acc[0]; facc[1] = acc[1];
#pragma unroll
            for (int r = 0; r < 4; ++r) {
                facc[2][r] = hacc[1][lane][r];
                facc[3][r] = hacc[1][lane][4 + r];
            }
        } else {
#pragma unroll
            for (int r = 0; r < 4; ++r) {
                facc[0][r] = hacc[0][lane][r];
                facc[1][r] = hacc[0][lane][4 + r];
            }
            facc[2] = acc[0]; facc[3] = acc[1];
        }

#pragma unroll
        for (int t = 0; t < 4; ++t)
#pragma unroll
            for (int r = 0; r < 4; ++r) facc[t][r] += bias[16 * t + 4 * g + r];

        float gm = -INFINITY;
#pragma unroll
        for (int t = 0; t < 4; ++t)
#pragma unroll
            for (int r = 0; r < 4; ++r)
                if (16 * t + 4 * g + r < D_BINS) gm = fmaxf(gm, facc[t][r]);
        gm = fmaxf(gm, __shfl_xor(gm, 16));
        gm = fmaxf(gm, __shfl_xor(gm, 32));
        float ls = 0.f;
#pragma unroll
        for (int t = 0; t < 4; ++t)
#pragma unroll
            for (int r = 0; r < 4; ++r)
                if (16 * t + 4 * g + r < D_BINS) {
                    const float e = __expf(facc[t][r] - gm);
                    facc[t][r] = e;
                    ls += e;
                }
        ls += __shfl_xor(ls, 16);
        ls += __shfl_xor(ls, 32);
        const float inv = 1.f / ls;

        unsigned uc[4][4];
#pragma unroll
        for (int t = 0; t < 4; ++t)
#pragma unroll
            for (int r = 0; r < 4; ++r) {
                const int o = 16 * t + 4 * g + r;
                if (o < D_BINS && own) {
                    const int2 q = gg_[t][r];
                    const int tile = (q.x >> 3) * 8 + (q.y >> 4);
                    const int cell = (q.x & 7) * 16 + (q.y & 15);
                    uc[t][r] = (unsigned)((tile << 7) | cell);
                    atomicAdd(&lh[tile], 1);
                }
            }
        __syncthreads();   // SYNC3

        if (wv == 0) {
            const int l2 = 2 * lane;
            const int a = lh[l2];
            const int b = lh[l2 + 1];
            const int p = a + b;
            int incl = p;
#pragma unroll
            for (int off = 1; off < 64; off <<= 1) {
                const int t = __shfl_up(incl, off);
                if (lane >= off) incl += t;
            }
            const int excl = incl - p;
            lofs[l2]     = excl;
            lofs[l2 + 1] = excl + a;
            cntmat_t[(size_t)l2 * NBLK + blkid]       = a;
            cntmat_t[(size_t)(l2 + 1) * NBLK + blkid] = b;
            ofsmat_t[(size_t)l2 * NBLK + blkid]       = excl;
            ofsmat_t[(size_t)(l2 + 1) * NBLK + blkid] = excl + a;
        }
        __syncthreads();   // SYNC4

        uint2* dst = plist + (size_t)blkid * EPB;
        const unsigned ctxoff = (unsigned)((bn * PIXELS + pxg) * CTX);
#pragma unroll
        for (int t = 0; t < 4; ++t)
#pragma unroll
            for (int r = 0; r < 4; ++r) {
                const int o = 16 * t + 4 * g + r;
                if (o < D_BINS && own) {
                    const unsigned u = uc[t][r];
                    const int tl = (int)(u >> 7);
                    const int pos = lofs[tl] + atomicAdd(&lcur[tl], 1);
                    dst[pos] = make_uint2(__float_as_uint(facc[t][r] * inv),
                                          (ctxoff << 7) | (u & 127u));
                }
            }
    } else {
        // ========== ctx waves ==========
        const int T0 = (wv == 2) ? 3 : 6;
#pragma unroll
        for (int t = 0; t < 3; ++t)
#pragma unroll
            for (int r = 0; r < 4; ++r) {
                const int o = (T0 + t) * 16 + 4 * g + r;     // 48..143
                const int c = o - D_BINS;                    // -11..84
                if (c >= 0 && c < CTX)
                    sctx[m][c] = f2bf(acc[t][r] + bias[o]);
            }
        __syncthreads();   // SYNC2

        const char* sb = (const char*)sctx;
        char* gb = (char*)ctx + ((size_t)(bn * PIXELS) + p0) * CTX * 2;
        for (int i = lane + (wv == 2 ? 0 : 64); i < PXT * CTX * 2 / 16; i += 128)
            *(float4*)(gb + i * 16) = *(const float4*)(sb + i * 16);

        __syncthreads();   // SYNC3
        __syncthreads();   // SYNC4
    }
}

// ---------------------------------------------------------------------------
// Kernel 2 (gather): EXACT r11 version (8-pt MLP accumulate, 1024 threads).
// ---------------------------------------------------------------------------
__global__ __launch_bounds__(1024) void gather_kernel(
    const uint2* __restrict__ plist,
    const int*   __restrict__ cntmat_t,   // [NTILE][NBLK]
    const int*   __restrict__ ofsmat_t,   // [NTILE][NBLK]
    const unsigned short* __restrict__ ctx,
    float*       __restrict__ out)
{
    __shared__ float sacc[CTX][TCELLS + 1];   // 41.3 KB
    __shared__ uint2 bufB[CAPP];              // 29.7 KB
    __shared__ int segcnt[SEGS], segofsL[SEGS], segofsG[SEGS];
    __shared__ int cellcnt[TCELLS], celloff[TCELLS], cellcur[TCELLS];
    __shared__ int sTotal;
    uint2* bufA = (uint2*)sacc;               // overlay: bufA dead once sacc live

    const int tid    = threadIdx.x;
    const int wv     = tid >> 6;
    const int lane   = tid & 63;
    const int bucket = blockIdx.x;
    const int b      = bucket >> 7;
    const int tile   = bucket & 127;
    const int blk0   = b * SEGS;

    // phase 1: coalesced metadata loads + cellcnt zero
    if (tid < SEGS) {
        segcnt[tid]  = cntmat_t[(size_t)tile * NBLK + blk0 + tid];
        segofsG[tid] = ofsmat_t[(size_t)tile * NBLK + blk0 + tid];
    }
    if (tid >= 512 && tid < 512 + TCELLS) cellcnt[tid - 512] = 0;
    __syncthreads();

    // phase 2: wave 0 shfl-scans the 264 segment counts (5 chunks, carry)
    if (wv == 0) {
        int carry = 0;
#pragma unroll
        for (int c = 0; c < 5; ++c) {
            const int i = c * 64 + lane;
            const int v = (i < SEGS) ? segcnt[i] : 0;
            int incl = v;
#pragma unroll
            for (int off = 1; off < 64; off <<= 1) {
                const int t = __shfl_up(incl, off);
                if (lane >= off) incl += t;
            }
            if (i < SEGS) segofsL[i] = carry + incl - v;
            carry += __shfl(incl, 63);
        }
        if (lane == 0) sTotal = carry;
    }
    __syncthreads();
    const int total = sTotal;
    const int ncap  = (total < CAP) ? total : CAP;

    // phase 3: copy segments -> bufA AND build LDS cell histogram (fused)
    {
        const int sub = lane >> 3;
        const int sl  = lane & 7;
        for (int sgi = wv * 8 + sub; sgi < SEGS; sgi += 128) {
            const int n = segcnt[sgi];
            if (!n) continue;
            const int dstb = segofsL[sgi];
            const uint2* sp = plist + (size_t)(blk0 + sgi) * EPB + segofsG[sgi];
            for (int i = sl; i < n; i += 8) {
                const int d = dstb + i;
                if (d < CAP) {
                    const uint2 e = sp[i];
                    bufA[d] = e;
                    atomicAdd(&cellcnt[e.y & 127u], 1);
                }
            }
        }
    }
    __syncthreads();

    // phase 4: wave 1 shfl-scans the 128 cell counts padded to 8
    if (wv == 1) {
        int carry = 0;
#pragma unroll
        for (int c = 0; c < 2; ++c) {
            const int i = c * 64 + lane;
            const int pv = (cellcnt[i] + 7) & ~7;
            int incl = pv;
#pragma unroll
            for (int off = 1; off < 64; off <<= 1) {
                const int t = __shfl_up(incl, off);
                if (lane >= off) incl += t;
            }
            celloff[i] = carry + incl - pv;
            cellcur[i] = 0;
            carry += __shfl(incl, 63);
        }
    }
    __syncthreads();

    // phase 5: zero pad slots (disjoint) + reorder bufA -> bufB cell-sorted
    if (tid < TCELLS) {
        const int o = celloff[tid] + cellcnt[tid];
        const int e = celloff[tid] + ((cellcnt[tid] + 7) & ~7);
        for (int i = o; i < e; ++i) bufB[i] = make_uint2(0u, 0u);
    }
    for (int i = tid; i < ncap; i += 1024) {
        const uint2 e = bufA[i];
        const int c = (int)(e.y & 127u);
        bufB[celloff[c] + atomicAdd(&cellcur[c], 1)] = e;
    }
    __syncthreads();   // bufA dead; sacc live from here

    // accumulate: wave wv owns cells c = wv, wv+16, ...; lane l<40 owns
    // channels (2l, 2l+1); 8-pt unrolled, 8 independent loads in flight.
    for (int c = wv; c < TCELLS; c += 16) {
        const int s0 = celloff[c];
        const int pc = (cellcnt[c] + 7) & ~7;
        float a0 = 0.f, a1 = 0.f;
        for (int i = 0; i < pc; i += 8) {
            uint2 e[8];
#pragma unroll
            for (int r = 0; r < 8; ++r) e[r] = bufB[s0 + i + r];   // broadcast
            if (lane < 40) {
                unsigned u[8];
#pragma unroll
                for (int r = 0; r < 8; ++r)
                    u[r] = *(const unsigned*)(ctx + (e[r].y >> 7) + 2 * lane);
#pragma unroll
                for (int r = 0; r < 8; ++r) {
                    const float d  = __uint_as_float(e[r].x);
                    a0 += d * __uint_as_float(u[r] << 16);
                    a1 += d * __uint_as_float(u[r] & 0xffff0000u);
                }
            }
        }
        if (lane < 40) {
            sacc[2 * lane][c]     = a0;
            sacc[2 * lane + 1][c] = a1;
        }
    }

    // slow path for bucket overflow (~30 sigma; correctness only)
    if (total > CAP) {
        for (int sgi = 0; sgi < SEGS; ++sgi) {
            const int dstb = segofsL[sgi];
            const int n    = segcnt[sgi];
            if (dstb + n <= CAP) continue;
            const uint2* sp = plist + (size_t)(blk0 + sgi) * EPB + segofsG[sgi];
            const int i0 = (CAP > dstb) ? (CAP - dstb) : 0;
            for (int i = i0; i < n; ++i) {
                const uint2 e = sp[i];
                const int c = (int)(e.y & 127u);
                if ((c & 15) == wv && lane < 40) {
                    const unsigned u = *(const unsigned*)(ctx + (e.y >> 7) + 2 * lane);
                    const float dep = __uint_as_float(e.x);
                    sacc[2 * lane][c]     += dep * __uint_as_float(u << 16);
                    sacc[2 * lane + 1][c] += dep * __uint_as_float(u & 0xffff0000u);
                }
            }
        }
    }
    __syncthreads();

    // epilogue: full 64B line writes to (B,C,H,W)
    const int tr = tile >> 3;
    const int tc = tile & 7;
    const int c0  = tid >> 4;
    const int col = tid & 15;
#pragma unroll
    for (int cc = c0; cc < CTX; cc += 64) {
#pragma unroll
        for (int r = 0; r < 8; ++r) {
            out[((size_t)(b * CTX + cc)) * BEVHW + (tr * 8 + r) * 128 + tc * 16 + col]
                = sacc[cc][r * 16 + col];
        }
    }
}

extern "C" void kernel_launch(void* const* d_in, const int* in_sizes, int n_in,
                              void* d_out, int out_size, void* d_ws, size_t ws_size,
                              hipStream_t stream)
{
    const float* img  = (const float*)d_in[0];
    const float* w    = (const float*)d_in[4];
    const float* bias = (const float*)d_in[5];
    const int*   geom = (const int*)d_in[6];
    float*       out  = (float*)d_out;

    float* ws = (float*)d_ws;
    unsigned short* wf = (unsigned short*)(ws + WHLF_OFF);
    __hip_bfloat16* ctx = (__hip_bfloat16*)(ws + CTX_OFF);
    int*   cntmat_t = (int*)(ws + CNTMAT_OFF);
    int*   ofsmat_t = (int*)(ws + OFSMAT_OFF);
    uint2* plist    = (uint2*)(ws + PLIST_OFF);

    // 0. W -> fragment-major bf16 hi/lo (147 KB, L2-resident)
    wsplit_kernel<<<144, 256, 0, stream>>>(w, wf);

    // 1. 4-wave blocks (r11-exact, session best)
    {
        dim3 grid(NPXT, BNPAIR);   // 1056 blocks x 256 threads
        gemm_fused<<<grid, 256, 0, stream>>>(img, wf, bias, geom, ctx,
                                             plist, cntmat_t, ofsmat_t);
    }

    // 2. gather: r11-exact, single launch
    gather_kernel<<<NBUCKET, 1024, 0, stream>>>(plist, cntmat_t, ofsmat_t,
                                                (const unsigned short*)ctx, out);
}